// Round 16
// baseline (93.452 us; speedup 1.0000x reference)
//
#include <hip/hip_runtime.h>

typedef __attribute__((ext_vector_type(8))) short short8;   // 8 bf16 = 4 VGPRs
typedef __attribute__((ext_vector_type(4))) float f32x4;

#define THREADS 256
#define WPB 4            // waves per block = images per block
#define N_PATCH 196
#define NCLS 10
#define FEAT 784
#define ROWSH 40         // ushorts per LDS row = 80 B (16B-aligned, non-pow2 stride)

union I4S8 { int i[4]; short8 v; };

// Input h in [0, 0.5] rad -> revolutions in [0, 0.08): no range reduction
// needed for v_sin/v_cos (hardware takes revolutions).
__device__ __forceinline__ float fast_sin(float h) {
    float r = h * 0.15915494309189535f, o;
    asm("v_sin_f32 %0, %1" : "=v"(o) : "v"(r));
    return o;
}
__device__ __forceinline__ float fast_cos(float h) {
    float r = h * 0.15915494309189535f, o;
    asm("v_cos_f32 %0, %1" : "=v"(o) : "v"(r));
    return o;
}

// trig -> product state -> exact hi/lo bf16 split -> pack -> stage 64 B to LDS
__device__ __forceinline__ void pack_store(unsigned short* rowp,
                                           float2 top, float2 bot, bool vld)
{
    const float c0 = fast_cos(0.5f * top.x), s0 = fast_sin(0.5f * top.x);
    const float c1 = fast_cos(0.5f * top.y), s1 = fast_sin(0.5f * top.y);
    const float c2 = fast_cos(0.5f * bot.x), s2 = fast_sin(0.5f * bot.x);
    const float c3 = fast_cos(0.5f * bot.y), s3 = fast_sin(0.5f * bot.y);

    const float wm = vld ? 1.f : 0.f;         // zero st => dead slots contribute 0
    const float p00 = wm * c0 * c1, p01 = wm * c0 * s1;
    const float p10 = wm * s0 * c1, p11 = wm * s0 * s1;
    const float q00 = c2 * c3, q01 = c2 * s3, q10 = s2 * c3, q11 = s2 * s3;
    float st[16];
    st[ 0]=p00*q00; st[ 1]=p00*q01; st[ 2]=p00*q10; st[ 3]=p00*q11;
    st[ 4]=p01*q00; st[ 5]=p01*q01; st[ 6]=p01*q10; st[ 7]=p01*q11;
    st[ 8]=p10*q00; st[ 9]=p10*q01; st[10]=p10*q10; st[11]=p10*q11;
    st[12]=p11*q00; st[13]=p11*q01; st[14]=p11*q10; st[15]=p11*q11;

    I4S8 h0, h1, l0, l1;
#pragma unroll
    for (int j = 0; j < 8; ++j) {
        const unsigned b0 = __float_as_uint(st[2*j]);
        const unsigned b1 = __float_as_uint(st[2*j+1]);
        const unsigned hp = __builtin_amdgcn_perm(b1, b0, 0x07060302u);
        const unsigned lb0 = __float_as_uint(st[2*j]   - __uint_as_float(b0 & 0xffff0000u));
        const unsigned lb1 = __float_as_uint(st[2*j+1] - __uint_as_float(b1 & 0xffff0000u));
        const unsigned lp = __builtin_amdgcn_perm(lb1, lb0, 0x07060302u);
        if (j < 4) { h0.i[j] = (int)hp; l0.i[j] = (int)lp; }
        else       { h1.i[j-4] = (int)hp; l1.i[j-4] = (int)lp; }
    }
    *(short8*)(rowp +  0) = h0.v;   // k  0..7  (hi d0..7)
    *(short8*)(rowp +  8) = h1.v;   // k  8..15 (hi d8..15)
    *(short8*)(rowp + 16) = l0.v;   // k 16..23 (lo d0..7)
    *(short8*)(rowp + 24) = l1.v;   // k 24..31 (lo d8..15)
}

// Max-threads bound only: min-waves bounds clamp VGPR to 32-36 and serialize
// the inner loop (r11/r13: both pipes <50% busy).
__global__ __launch_bounds__(THREADS)
void quanv_mfma_kernel(const float* __restrict__ x,
                       const float* __restrict__ U,
                       const float* __restrict__ W,
                       const float* __restrict__ b,
                       float* __restrict__ out, int n_img)
{
    // double-buffered staging: stage it+1 while consuming it
    __shared__ unsigned short sB[WPB][2][64][ROWSH];   // 40 KB -> 4 blocks/CU
    __shared__ float sLog[WPB][16];

    const int t    = threadIdx.x;
    const int w    = t >> 6;
    const int lane = t & 63;
    const int img  = blockIdx.x * WPB + w;
    if (img >= n_img) return;                 // no inter-wave sync anywhere

    const int colc = lane & 15;               // MFMA column / A row owner
    const int kb   = lane >> 4;               // k-block 0..3
    const float sgn0 = (kb & 2) ? -1.f : 1.f; // e bit3 (wire 0) sign, e = 4*kb+reg
    const float sgn1 = (kb & 1) ? -1.f : 1.f; // e bit2 (wire 1) sign
    // class split across kb-groups: {0,1,2} {3,4,5} {6,7} {8,9}
    const int cbase = (kb < 2) ? 3 * kb : (6 + 2 * (kb - 2));
    const int ccnt  = (kb < 2) ? 3 : 2;

    // ---- A fragments from U, loaded ONCE: A1=[Uhi|Uhi], A2=[Ulo|0] ----
    short8 a1, a2;
    {
        const float* Urow = U + colc * 16 + (kb & 1) * 8;
        unsigned ub[8]; float uf[8];
#pragma unroll
        for (int i = 0; i < 8; ++i) { uf[i] = Urow[i]; ub[i] = __float_as_uint(uf[i]); }
        I4S8 hi, lo;
#pragma unroll
        for (int j = 0; j < 4; ++j)
            hi.i[j] = (int)__builtin_amdgcn_perm(ub[2*j+1], ub[2*j], 0x07060302u);
#pragma unroll
        for (int j = 0; j < 4; ++j) {
            unsigned lb0 = __float_as_uint(uf[2*j]   - __uint_as_float(ub[2*j]   & 0xffff0000u));
            unsigned lb1 = __float_as_uint(uf[2*j+1] - __uint_as_float(ub[2*j+1] & 0xffff0000u));
            lo.i[j] = (kb < 2) ? (int)__builtin_amdgcn_perm(lb1, lb0, 0x07060302u) : 0;
        }
        a1 = hi.v; a2 = lo.v;
    }

    const float* ximg = x + (size_t)img * FEAT;

    float accl[3] = {0.f, 0.f, 0.f};          // my kb-group's 2-3 classes

    // ---- prologue: stage it=0 into buf0; prefetch pixels for it=1 ----
    float2 top, bot;
    {
        const int r = lane / 14, cl = lane - r * 14;   // it=0 always valid
        const float* px = ximg + r * 56 + cl * 2;
        top = *(const float2*)px;
        bot = *(const float2*)(px + 28);
    }
    pack_store(&sB[w][0][lane][0], top, bot, true);
    {
        const int pmn = 64 + lane;                     // it=1 always valid
        const int r = pmn / 14, cl = pmn - r * 14;
        const float* px = ximg + r * 56 + cl * 2;
        top = *(const float2*)px;
        bot = *(const float2*)(px + 28);
    }

#pragma unroll 1
    for (int it = 0; it < 4; ++it) {
        const int cur = it & 1;

        // ---- stage it+1 into the spare buffer (hides under this iter's
        //      MFMA/fold; the cur-buffer data was written one phase ago) ----
        if (it < 3) {
            pack_store(&sB[w][cur ^ 1][lane][0], top, bot,
                       (it + 1) * 64 + lane < N_PATCH);
            if (it < 2) {
                const int pmn = (it + 2) * 64 + lane;
                const int pcn = (pmn < N_PATCH) ? pmn : N_PATCH - 1;
                const int r = pcn / 14, cl = pcn - r * 14;
                const float* px = ximg + r * 56 + cl * 2;
                top = *(const float2*)px;
                bot = *(const float2*)(px + 28);
            }
        }

        // ---- consume buf[cur]: 4 fragments, 8 MFMAs, 4 independent accs ----
        const short8 bf0 = *(const short8*)&sB[w][cur][ 0 + colc][8 * kb];
        const short8 bf1 = *(const short8*)&sB[w][cur][16 + colc][8 * kb];
        const short8 bf2 = *(const short8*)&sB[w][cur][32 + colc][8 * kb];
        const short8 bf3 = *(const short8*)&sB[w][cur][48 + colc][8 * kb];

        f32x4 v0 = {0.f,0.f,0.f,0.f}, v1 = v0, v2 = v0, v3 = v0;
        v0 = __builtin_amdgcn_mfma_f32_16x16x32_bf16(a1, bf0, v0, 0, 0, 0);
        v1 = __builtin_amdgcn_mfma_f32_16x16x32_bf16(a1, bf1, v1, 0, 0, 0);
        v2 = __builtin_amdgcn_mfma_f32_16x16x32_bf16(a1, bf2, v2, 0, 0, 0);
        v3 = __builtin_amdgcn_mfma_f32_16x16x32_bf16(a1, bf3, v3, 0, 0, 0);
        v0 = __builtin_amdgcn_mfma_f32_16x16x32_bf16(a2, bf0, v0, 0, 0, 0);
        v1 = __builtin_amdgcn_mfma_f32_16x16x32_bf16(a2, bf1, v1, 0, 0, 0);
        v2 = __builtin_amdgcn_mfma_f32_16x16x32_bf16(a2, bf2, v2, 0, 0, 0);
        v3 = __builtin_amdgcn_mfma_f32_16x16x32_bf16(a2, bf3, v3, 0, 0, 0);

        // ---- per group: partial walsh -> kb-reduce (2 shfl) -> split fold ----
#pragma unroll
        for (int g = 0; g < 4; ++g) {
            const f32x4 amv = (g == 0) ? v0 : (g == 1) ? v1 : (g == 2) ? v2 : v3;
            const float sq0 = amv[0]*amv[0], sq1 = amv[1]*amv[1];
            const float sq2 = amv[2]*amv[2], sq3 = amv[3]*amv[3];
            const float t01 = sq0 + sq1, t23 = sq2 + sq3, sall = t01 + t23;
            float m0 = sgn0 * sall;
            float m1 = sgn1 * sall;
            float m2 = t01 - t23;
            float m3 = (sq0 - sq1) + (sq2 - sq3);

            m0 += __shfl_xor(m0, 16, 64); m0 += __shfl_xor(m0, 32, 64);
            m1 += __shfl_xor(m1, 16, 64); m1 += __shfl_xor(m1, 32, 64);
            m2 += __shfl_xor(m2, 16, 64); m2 += __shfl_xor(m2, 32, 64);
            m3 += __shfl_xor(m3, 16, 64); m3 += __shfl_xor(m3, 32, 64);

            const int pg  = it * 64 + 16 * g + colc;
            const int pcl = (pg < N_PATCH) ? pg : N_PATCH - 1;  // m's are 0 there
#pragma unroll
            for (int cc = 0; cc < 3; ++cc) {
                const int  c     = cbase + cc;
                const bool cval  = (cc < ccnt);
                const int  cSafe = (c < NCLS) ? c : NCLS - 1;
                const float4 wv = *(const float4*)&W[cSafe * FEAT + 4 * pcl];
                const float contrib = m0*wv.x + m1*wv.y + m2*wv.z + m3*wv.w;
                accl[cc] += cval ? contrib : 0.f;
            }
        }
    }

    // ---- reduce my classes over colc (within kb-group) ----
#pragma unroll
    for (int cc = 0; cc < 3; ++cc) {
        float v = accl[cc];
        v += __shfl_xor(v, 1, 64);
        v += __shfl_xor(v, 2, 64);
        v += __shfl_xor(v, 4, 64);
        v += __shfl_xor(v, 8, 64);
        accl[cc] = v;
    }

    // one lane per kb-group publishes its classes (intra-wave, in-order DS)
    if (colc == 0) {
#pragma unroll
        for (int cc = 0; cc < 3; ++cc)
            if (cc < ccnt) sLog[w][cbase + cc] = accl[cc] + b[cbase + cc];
    }
    asm volatile("s_waitcnt lgkmcnt(0)" ::: "memory");

    float lg[NCLS];
#pragma unroll
    for (int c = 0; c < NCLS; ++c) lg[c] = sLog[w][c];

    float m = lg[0];
#pragma unroll
    for (int c = 1; c < NCLS; ++c) m = fmaxf(m, lg[c]);
    float ssum = 0.f;
#pragma unroll
    for (int c = 0; c < NCLS; ++c) ssum += __expf(lg[c] - m);
    const float ls = __logf(ssum);

    if (lane < NCLS)
        out[(size_t)img * NCLS + lane] = lg[lane] - m - ls;
}

extern "C" void kernel_launch(void* const* d_in, const int* in_sizes, int n_in,
                              void* d_out, int out_size, void* d_ws, size_t ws_size,
                              hipStream_t stream) {
    const float* x = (const float*)d_in[0];
    const float* U = (const float*)d_in[1];
    const float* W = (const float*)d_in[2];
    const float* b = (const float*)d_in[3];
    float* out = (float*)d_out;

    const int n_img = in_sizes[0] / FEAT;            // 8192
    const int grid  = (n_img + WPB - 1) / WPB;       // 2048 blocks

    quanv_mfma_kernel<<<grid, THREADS, 0, stream>>>(x, U, W, b, out, n_img);
}